// Round 16
// baseline (285.049 us; speedup 1.0000x reference)
//
#include <hip/hip_runtime.h>
#include <hip/hip_bf16.h>
#include <stdint.h>

#define B_    4
#define NN    4096
#define DIN   512
#define DOUT  256
#define ALPHA_ 0.2f

typedef __attribute__((ext_vector_type(8))) short short8;
typedef __attribute__((ext_vector_type(4))) float f32x4;
typedef __attribute__((ext_vector_type(2))) float f32x2;

typedef const __attribute__((address_space(1))) void gconst_void;
typedef __attribute__((address_space(3))) void lds_void;

__device__ __forceinline__ unsigned short f2bf(float x) {
    union { float f; uint32_t u; } v; v.f = x;
    uint32_t r = v.u + 0x7FFFu + ((v.u >> 16) & 1u);
    return (unsigned short)(r >> 16);
}

// ---------------- K_prep: grid-stride (2048 blocks): pack adj | h->bf16 | WsT -------
__global__ __launch_bounds__(256) void k_prep(const int* __restrict__ adj,
                                              const float4* __restrict__ h4,
                                              const float* __restrict__ Ws,
                                              uint32_t* __restrict__ bits,
                                              uint2* __restrict__ hb,
                                              unsigned short* __restrict__ wst) {
    const int gt = blockIdx.x * 256 + threadIdx.x;
    const int NT = 2048 * 256;
    for (int idx = gt; idx < NN * NN; idx += NT) {
        unsigned long long m = __ballot(adj[idx] > 0);
        if ((threadIdx.x & 63) == 0)
            *reinterpret_cast<unsigned long long*>(bits + ((idx >> 6) << 1)) = m;
    }
    for (int idx = gt; idx < B_ * NN * DIN / 4; idx += NT) {
        float4 v = h4[idx];
        uint2 o;
        o.x = (uint32_t)f2bf(v.x) | ((uint32_t)f2bf(v.y) << 16);
        o.y = (uint32_t)f2bf(v.z) | ((uint32_t)f2bf(v.w) << 16);
        hb[idx] = o;
    }
    for (int idx = gt; idx < B_ * DOUT * DIN; idx += NT) {
        int k = idx & (DIN - 1);
        int o = (idx >> 9) & (DOUT - 1);
        int b = idx >> 17;
        wst[idx] = f2bf(Ws[((size_t)b * DIN + k) * DOUT + o]);
    }
}

// ---------------- K1: WhT = (h@Ws)^T + fused e1/e2 -> factorized exp tables --------
__global__ __launch_bounds__(256) void k_gemm1(const unsigned short* __restrict__ hb,
                                               const unsigned short* __restrict__ wst,
                                               const float* __restrict__ a,
                                               unsigned short* __restrict__ wht,
                                               float2* __restrict__ x1t,
                                               float* __restrict__ y1t,
                                               float* __restrict__ y2t) {
    __shared__ unsigned short Ah[64 * 64];
    __shared__ unsigned short Bw[256 * 64];
    __shared__ float e1s[64], e2s[64];
    const int tid = threadIdx.x;
    const int w = tid >> 6, lane = tid & 63;
    const int l15 = lane & 15, lhi = lane >> 4;
    const int b = blockIdx.y;
    const int n0 = blockIdx.x * 64;
    const unsigned short* hrow = hb + ((size_t)b * NN + n0) * DIN;
    const unsigned short* wrow = wst + (size_t)b * DOUT * DIN;

    if (tid < 64) { e1s[tid] = 0.f; e2s[tid] = 0.f; }

    f32x4 acc[4][4] = {};

    for (int kt = 0; kt < DIN / 64; ++kt) {
        const int k0 = kt * 64;
        #pragma unroll
        for (int it = 0; it < 2; ++it) {
            int q = it * 256 + tid;
            int row = q >> 3, c = q & 7;
            const unsigned short* src = hrow + (size_t)row * DIN + k0 + 8 * (c ^ (row & 7));
            char* dst = reinterpret_cast<char*>(Ah) + it * 4096 + w * 1024;
            __builtin_amdgcn_global_load_lds((gconst_void*)src, (lds_void*)dst, 16, 0, 0);
        }
        #pragma unroll
        for (int it = 0; it < 8; ++it) {
            int q = it * 256 + tid;
            int row = q >> 3, c = q & 7;
            const unsigned short* src = wrow + (size_t)row * DIN + k0 + 8 * (c ^ (row & 7));
            char* dst = reinterpret_cast<char*>(Bw) + it * 4096 + w * 1024;
            __builtin_amdgcn_global_load_lds((gconst_void*)src, (lds_void*)dst, 16, 0, 0);
        }
        __syncthreads();
        #pragma unroll
        for (int kk = 0; kk < 2; ++kk) {
            short8 af[4], bfr[4];
            #pragma unroll
            for (int rf = 0; rf < 4; ++rf) {
                int row = rf * 16 + l15;
                int off = row * 128 + ((kk * 64 + lhi * 16) ^ ((row & 7) << 4));
                af[rf] = *reinterpret_cast<const short8*>(reinterpret_cast<const char*>(Ah) + off);
            }
            #pragma unroll
            for (int cf = 0; cf < 4; ++cf) {
                int row = w * 64 + cf * 16 + l15;
                int off = row * 128 + ((kk * 64 + lhi * 16) ^ ((row & 7) << 4));
                bfr[cf] = *reinterpret_cast<const short8*>(reinterpret_cast<const char*>(Bw) + off);
            }
            #pragma unroll
            for (int rf = 0; rf < 4; ++rf)
                #pragma unroll
                for (int cf = 0; cf < 4; ++cf)
                    acc[rf][cf] = __builtin_amdgcn_mfma_f32_16x16x32_bf16(af[rf], bfr[cf], acc[rf][cf], 0, 0, 0);
        }
        __syncthreads();
    }
    unsigned short* wb = wht + (size_t)b * DOUT * NN;
    #pragma unroll
    for (int rf = 0; rf < 4; ++rf) {
        #pragma unroll
        for (int cf = 0; cf < 4; ++cf) {
            int d = w * 64 + cf * 16 + l15;
            int m = n0 + rf * 16 + lhi * 4;
            uint2 pk;
            pk.x = (uint32_t)f2bf(acc[rf][cf][0]) | ((uint32_t)f2bf(acc[rf][cf][1]) << 16);
            pk.y = (uint32_t)f2bf(acc[rf][cf][2]) | ((uint32_t)f2bf(acc[rf][cf][3]) << 16);
            *reinterpret_cast<uint2*>(wb + (size_t)d * NN + m) = pk;
        }
    }
    const float* ab = a + b * 2 * DOUT;
    float a1v[4], a2v[4];
    #pragma unroll
    for (int cf = 0; cf < 4; ++cf) {
        int d = w * 64 + cf * 16 + l15;
        a1v[cf] = ab[d];
        a2v[cf] = ab[DOUT + d];
    }
    #pragma unroll
    for (int rf = 0; rf < 4; ++rf) {
        #pragma unroll
        for (int j = 0; j < 4; ++j) {
            float p1 = 0.f, p2 = 0.f;
            #pragma unroll
            for (int cf = 0; cf < 4; ++cf) {
                p1 = fmaf(acc[rf][cf][j], a1v[cf], p1);
                p2 = fmaf(acc[rf][cf][j], a2v[cf], p2);
            }
            #pragma unroll
            for (int msk = 1; msk < 16; msk <<= 1) {
                p1 += __shfl_xor(p1, msk);
                p2 += __shfl_xor(p2, msk);
            }
            if (l15 == 0) {
                atomicAdd(&e1s[rf * 16 + lhi * 4 + j], p1);
                atomicAdd(&e2s[rf * 16 + lhi * 4 + j], p2);
            }
        }
    }
    __syncthreads();
    if (tid < 64) {
        float e1v = e1s[tid], e2v = e2s[tid];
        x1t[b * NN + n0 + tid] = float2{__expf(e1v), __expf(ALPHA_ * e1v)};
        y1t[b * NN + n0 + tid] = __expf(e2v);
        y2t[b * NN + n0 + tid] = __expf(ALPHA_ * e2v);
    }
}

// ---------------- K4: h' = softmax(P)@Wh, K-split x2, FUSED pairwise finalize ------
// R11 body (64n x 256d x half-K, 512 thr, 1 barrier/tile, plain-store partials).
// NEW: partner blocks (same b,n0; T0 0/1) are on the SAME XCD (bid&7 equal), so the
// second-arriving block combines partner's L2-resident partial with its in-register
// acc, normalizes, applies ELU, writes out. Eliminates k_final.
__global__ __launch_bounds__(512, 4) void k_attn(const unsigned short* __restrict__ wht,
                                                 const uint32_t* __restrict__ bits,
                                                 const float2* __restrict__ x1t,
                                                 const float* __restrict__ y1t,
                                                 const float* __restrict__ y2t,
                                                 float* __restrict__ part0,
                                                 float* __restrict__ part1,
                                                 float* __restrict__ sums0,
                                                 float* __restrict__ sums1,
                                                 int* __restrict__ flags,
                                                 float* __restrict__ out) {
    __shared__ unsigned short Bw[2 * 256 * 64];  // WhT tile dbuf, swizzled rows (64KB)
    __shared__ unsigned short Pt[2 * 64 * 64];   // P tile dbuf, swizzled rows (16KB)

    const int tid = threadIdx.x;
    const int w = tid >> 6, lane = tid & 63;
    const int l15 = lane & 15, lh4 = lane >> 4;
    const int wn = w >> 2, wd = w & 3;

    // XCD swizzle: 512 blocks; xcd g = (b, n-half); within: 32 n-chunks x 2 k-halves
    const int bid = blockIdx.x;
    const int wg = ((bid & 7) << 6) | (bid >> 3);
    const int g  = wg >> 6;
    const int b  = g >> 1;
    const int n0 = ((g & 1) * 32 + (wg & 31)) << 6;
    const int T0 = ((wg >> 5) & 1) * 32;         // k-half: tiles [T0, T0+32)
    const int pairid = g * 32 + (wg & 31);       // 256 pairs

    // P mapping: pr = row (0..63), pc = 8-m group (0..7)
    const int pr = tid >> 3, pc = tid & 7;
    const float2 xv = x1t[b * NN + n0 + pr];
    const float X1 = xv.x, X2 = xv.y;
    const unsigned short* wb = wht + (size_t)b * DOUT * NN;

    f32x4 acc[2][4] = {};
    f32x4 accs[2] = {};
    short8 ones;
    {
        union { short8 v; uint32_t u[4]; } ov;
        ov.u[0] = 0x3F803F80u; ov.u[1] = 0x3F803F80u;
        ov.u[2] = 0x3F803F80u; ov.u[3] = 0x3F803F80u;
        ones = ov.v;
    }

    // strength-reduced pointers
    const unsigned short* sp[4];
    #pragma unroll
    for (int it = 0; it < 4; ++it) {
        int q = it * 512 + tid;
        int row = q >> 3, c = q & 7;
        sp[it] = wb + (size_t)row * NN + T0 * 64 + 8 * (c ^ (row & 7));
    }
    const uint8_t* bp = reinterpret_cast<const uint8_t*>(bits) +
                        (size_t)(n0 + pr) * (NN / 8) + T0 * 8 + pc;
    const float4* y1p = reinterpret_cast<const float4*>(y1t + b * NN + T0 * 64 + pc * 8);
    const float4* y2p = reinterpret_cast<const float4*>(y2t + b * NN + T0 * 64 + pc * 8);

#define STAGE(BUF)                                                                     \
    {                                                                                  \
        _Pragma("unroll")                                                              \
        for (int it = 0; it < 4; ++it) {                                               \
            char* dst = reinterpret_cast<char*>(Bw) + (BUF) * 32768 + it * 8192 + w * 1024; \
            __builtin_amdgcn_global_load_lds((gconst_void*)sp[it], (lds_void*)dst, 16, 0, 0); \
            sp[it] += 64;                                                              \
        }                                                                              \
    }

#define P_MATH(BB, Y1A, Y1B, Y2A, Y2B, PKW)                                            \
    {                                                                                  \
        float v1[8] = {Y1A.x, Y1A.y, Y1A.z, Y1A.w, Y1B.x, Y1B.y, Y1B.z, Y1B.w};        \
        float v2[8] = {Y2A.x, Y2A.y, Y2A.z, Y2A.w, Y2B.x, Y2B.y, Y2B.z, Y2B.w};        \
        _Pragma("unroll")                                                              \
        for (int i = 0; i < 4; ++i) {                                                  \
            f32x2 pa = f32x2{v1[2 * i], v1[2 * i + 1]} * X1;                           \
            f32x2 pb = f32x2{v2[2 * i], v2[2 * i + 1]} * X2;                           \
            f32x2 pm = __builtin_elementwise_max(pa, pb);                              \
            union { __hip_bfloat162 h; uint32_t u; } cc;                               \
            cc.h = __float22bfloat162_rn(float2{pm.x, pm.y});                          \
            uint32_t b2 = ((BB) >> (2 * i)) & 3u;                                      \
            uint32_t mk = ((b2 & 1u) ? 0xFFFFu : 0u) | ((b2 & 2u) ? 0xFFFF0000u : 0u); \
            PKW[i] = cc.u & mk;                                                        \
        }                                                                              \
    }

#define PT_WRITE(PKW, BUF)                                                             \
    {                                                                                  \
        uint4 qv; qv.x = PKW[0]; qv.y = PKW[1]; qv.z = PKW[2]; qv.w = PKW[3];          \
        *reinterpret_cast<uint4*>(reinterpret_cast<char*>(Pt) + (BUF) * 8192 +         \
                                  pr * 128 + ((pc * 16) ^ ((pr & 7) << 4))) = qv;      \
    }

#define MM(CUR)                                                                        \
    {                                                                                  \
        const char* bwb = reinterpret_cast<const char*>(Bw) + (CUR) * 32768;           \
        const char* ptb = reinterpret_cast<const char*>(Pt) + (CUR) * 8192;            \
        __builtin_amdgcn_s_setprio(1);                                                 \
        _Pragma("unroll")                                                              \
        for (int kk = 0; kk < 2; ++kk) {                                               \
            short8 af[2], bf[4];                                                       \
            _Pragma("unroll")                                                          \
            for (int rf = 0; rf < 2; ++rf) {                                           \
                int row = wn * 32 + rf * 16 + l15;                                     \
                int off = row * 128 + ((kk * 64 + lh4 * 16) ^ ((row & 7) << 4));       \
                af[rf] = *reinterpret_cast<const short8*>(ptb + off);                  \
            }                                                                          \
            _Pragma("unroll")                                                          \
            for (int cf = 0; cf < 4; ++cf) {                                           \
                int row = wd * 64 + cf * 16 + l15;                                     \
                int off = row * 128 + ((kk * 64 + lh4 * 16) ^ ((row & 7) << 4));       \
                bf[cf] = *reinterpret_cast<const short8*>(bwb + off);                  \
            }                                                                          \
            _Pragma("unroll")                                                          \
            for (int rf = 0; rf < 2; ++rf) {                                           \
                _Pragma("unroll")                                                      \
                for (int cf = 0; cf < 4; ++cf)                                         \
                    acc[rf][cf] = __builtin_amdgcn_mfma_f32_16x16x32_bf16(             \
                        af[rf], bf[cf], acc[rf][cf], 0, 0, 0);                         \
                accs[rf] = __builtin_amdgcn_mfma_f32_16x16x32_bf16(                    \
                    af[rf], ones, accs[rf], 0, 0, 0);                                  \
            }                                                                          \
        }                                                                              \
        __builtin_amdgcn_s_setprio(0);                                                 \
    }

    // ---- prologue ----
    STAGE(0)
    {
        uint32_t bb = *bp; bp += 8;
        float4 y1a = y1p[0], y1b = y1p[1]; y1p += 16;
        float4 y2a = y2p[0], y2b = y2p[1]; y2p += 16;
        uint32_t pkw[4];
        P_MATH(bb, y1a, y1b, y2a, y2b, pkw)
        PT_WRITE(pkw, 0)
    }
    __syncthreads();

    // ---- main loop over 32 tiles: ONE barrier per tile ----
    for (int t = 0; t < 32; ++t) {
        const int cur = t & 1;
        if (t < 31) {
            STAGE(cur ^ 1)
            uint32_t bb = *bp; bp += 8;
            float4 y1a = y1p[0], y1b = y1p[1]; y1p += 16;
            float4 y2a = y2p[0], y2b = y2p[1]; y2p += 16;
            uint32_t pkw[4];
            P_MATH(bb, y1a, y1b, y2a, y2b, pkw)
            PT_WRITE(pkw, cur ^ 1)
        }
        MM(cur)
        __syncthreads();
    }
#undef STAGE
#undef P_MATH
#undef PT_WRITE
#undef MM

    // ---- epilogue 1: plain-store own partial + row sums ----
    float* pdst = (T0 == 0) ? part0 : part1;
    #pragma unroll
    for (int rf = 0; rf < 2; ++rf) {
        #pragma unroll
        for (int cf = 0; cf < 4; ++cf) {
            int d = wd * 64 + cf * 16 + l15;
            #pragma unroll
            for (int j = 0; j < 4; ++j) {
                int nr = n0 + wn * 32 + rf * 16 + lh4 * 4 + j;
                pdst[((size_t)b * NN + nr) * DOUT + d] = acc[rf][cf][j];
            }
        }
    }
    if (wd == 0 && l15 == 0) {
        float* sdst = (T0 == 0) ? sums0 : sums1;
        #pragma unroll
        for (int rf = 0; rf < 2; ++rf)
            #pragma unroll
            for (int j = 0; j < 4; ++j) {
                int nr = n0 + wn * 32 + rf * 16 + lh4 * 4 + j;
                sdst[b * NN + nr] = accs[rf][j];
            }
    }

    // ---- epilogue 2: second-arriving block of the pair finalizes ----
    __threadfence();                      // agent-scope release of partial stores
    int* lflag = reinterpret_cast<int*>(Pt);   // Pt dead after loop (post-barrier)
    if (tid == 0) *lflag = atomicAdd(&flags[pairid], 1);
    __syncthreads();
    if (*lflag == 1) {
        __threadfence();                  // acquire: invalidate stale cache lines
        const float* ppart = (T0 == 0) ? part1 : part0;
        const float* osums = (T0 == 0) ? sums1 : sums0;
        #pragma unroll
        for (int rf = 0; rf < 2; ++rf) {
            float inv[4];
            #pragma unroll
            for (int j = 0; j < 4; ++j) {
                int nr = n0 + wn * 32 + rf * 16 + lh4 * 4 + j;
                inv[j] = 1.0f / (accs[rf][j] + osums[b * NN + nr]);
            }
            #pragma unroll
            for (int cf = 0; cf < 4; ++cf) {
                int d = wd * 64 + cf * 16 + l15;
                #pragma unroll
                for (int j = 0; j < 4; ++j) {
                    int nr = n0 + wn * 32 + rf * 16 + lh4 * 4 + j;
                    size_t idx = ((size_t)b * NN + nr) * DOUT + d;
                    float x = (acc[rf][cf][j] + ppart[idx]) * inv[j];
                    x = x > 0.f ? x : (__expf(x) - 1.f);
                    out[idx] = x;
                }
            }
        }
    }
}

extern "C" void kernel_launch(void* const* d_in, const int* in_sizes, int n_in,
                              void* d_out, int out_size, void* d_ws, size_t ws_size,
                              hipStream_t stream) {
    (void)in_sizes; (void)n_in; (void)out_size; (void)ws_size;
    const float* h   = (const float*)d_in[0];
    const int*   adj = (const int*)d_in[1];
    const float* Ws  = (const float*)d_in[2];
    const float* a   = (const float*)d_in[3];
    float* out = (float*)d_out;

    char* ws = (char*)d_ws;
    unsigned short* hb  = (unsigned short*)(ws);              // 16,777,216 B (part0 later)
    unsigned short* wst = (unsigned short*)(ws + 16777216);   //  1,048,576 B
    unsigned short* wht = (unsigned short*)(ws + 17825792);   //  8,388,608 B
    float2* x1t = (float2*)(ws + 26214400);                   //    131,072 B
    float*  y1t = (float*)(ws + 26345472);                    //     65,536 B
    float*  y2t = (float*)(ws + 26411008);                    //     65,536 B
    uint32_t* bits = (uint32_t*)(ws + 26476544);              //  2,097,152 B
    float* sums0 = (float*)(ws + 28573696);                   //     65,536 B
    float* sums1 = (float*)(ws + 28639232);                   //     65,536 B
    int*   flags = (int*)(ws + 28704768);                     //      1,024 B
    float* part0 = (float*)hb;                                // hb dead after k_gemm1
    float* part1 = (float*)(ws + 28835840);                   // 16,777,216 B (ws >= 62MB, R13-verified)

    hipMemsetAsync(flags, 0, 1024, stream);
    k_prep<<<dim3(2048), dim3(256), 0, stream>>>(adj, (const float4*)h, Ws,
                                                 bits, (uint2*)hb, wst);
    k_gemm1<<<dim3(NN / 64, B_), dim3(256), 0, stream>>>(hb, wst, a, wht, x1t, y1t, y2t);
    k_attn<<<dim3(512), dim3(512), 0, stream>>>(wht, bits, x1t, y1t, y2t,
                                                part0, part1, sums0, sums1, flags, out);
}

// Round 17
// 106.040 us; speedup vs baseline: 2.6881x; 2.6881x over previous
//
#include <hip/hip_runtime.h>
#include <hip/hip_bf16.h>
#include <stdint.h>

#define B_    4
#define NN    4096
#define DIN   512
#define DOUT  256
#define ALPHA_ 0.2f

typedef __attribute__((ext_vector_type(8))) short short8;
typedef __attribute__((ext_vector_type(4))) float f32x4;
typedef __attribute__((ext_vector_type(2))) float f32x2;

typedef const __attribute__((address_space(1))) void gconst_void;
typedef __attribute__((address_space(3))) void lds_void;

__device__ __forceinline__ unsigned short f2bf(float x) {
    union { float f; uint32_t u; } v; v.f = x;
    uint32_t r = v.u + 0x7FFFu + ((v.u >> 16) & 1u);
    return (unsigned short)(r >> 16);
}

// ---------------- K_prep: grid-stride (2048 blocks): pack adj | h->bf16 | WsT -------
__global__ __launch_bounds__(256) void k_prep(const int* __restrict__ adj,
                                              const float4* __restrict__ h4,
                                              const float* __restrict__ Ws,
                                              uint32_t* __restrict__ bits,
                                              uint2* __restrict__ hb,
                                              unsigned short* __restrict__ wst) {
    const int gt = blockIdx.x * 256 + threadIdx.x;
    const int NT = 2048 * 256;
    for (int idx = gt; idx < NN * NN; idx += NT) {
        unsigned long long m = __ballot(adj[idx] > 0);
        if ((threadIdx.x & 63) == 0)
            *reinterpret_cast<unsigned long long*>(bits + ((idx >> 6) << 1)) = m;
    }
    for (int idx = gt; idx < B_ * NN * DIN / 4; idx += NT) {
        float4 v = h4[idx];
        uint2 o;
        o.x = (uint32_t)f2bf(v.x) | ((uint32_t)f2bf(v.y) << 16);
        o.y = (uint32_t)f2bf(v.z) | ((uint32_t)f2bf(v.w) << 16);
        hb[idx] = o;
    }
    for (int idx = gt; idx < B_ * DOUT * DIN; idx += NT) {
        int k = idx & (DIN - 1);
        int o = (idx >> 9) & (DOUT - 1);
        int b = idx >> 17;
        wst[idx] = f2bf(Ws[((size_t)b * DIN + k) * DOUT + o]);
    }
}

// ---------------- K1: WhT = (h@Ws)^T + fused e1/e2 -> factorized exp tables --------
__global__ __launch_bounds__(256) void k_gemm1(const unsigned short* __restrict__ hb,
                                               const unsigned short* __restrict__ wst,
                                               const float* __restrict__ a,
                                               unsigned short* __restrict__ wht,
                                               float2* __restrict__ x1t,
                                               float* __restrict__ y1t,
                                               float* __restrict__ y2t) {
    __shared__ unsigned short Ah[64 * 64];
    __shared__ unsigned short Bw[256 * 64];
    __shared__ float e1s[64], e2s[64];
    const int tid = threadIdx.x;
    const int w = tid >> 6, lane = tid & 63;
    const int l15 = lane & 15, lhi = lane >> 4;
    const int b = blockIdx.y;
    const int n0 = blockIdx.x * 64;
    const unsigned short* hrow = hb + ((size_t)b * NN + n0) * DIN;
    const unsigned short* wrow = wst + (size_t)b * DOUT * DIN;

    if (tid < 64) { e1s[tid] = 0.f; e2s[tid] = 0.f; }

    f32x4 acc[4][4] = {};

    for (int kt = 0; kt < DIN / 64; ++kt) {
        const int k0 = kt * 64;
        #pragma unroll
        for (int it = 0; it < 2; ++it) {
            int q = it * 256 + tid;
            int row = q >> 3, c = q & 7;
            const unsigned short* src = hrow + (size_t)row * DIN + k0 + 8 * (c ^ (row & 7));
            char* dst = reinterpret_cast<char*>(Ah) + it * 4096 + w * 1024;
            __builtin_amdgcn_global_load_lds((gconst_void*)src, (lds_void*)dst, 16, 0, 0);
        }
        #pragma unroll
        for (int it = 0; it < 8; ++it) {
            int q = it * 256 + tid;
            int row = q >> 3, c = q & 7;
            const unsigned short* src = wrow + (size_t)row * DIN + k0 + 8 * (c ^ (row & 7));
            char* dst = reinterpret_cast<char*>(Bw) + it * 4096 + w * 1024;
            __builtin_amdgcn_global_load_lds((gconst_void*)src, (lds_void*)dst, 16, 0, 0);
        }
        __syncthreads();
        #pragma unroll
        for (int kk = 0; kk < 2; ++kk) {
            short8 af[4], bfr[4];
            #pragma unroll
            for (int rf = 0; rf < 4; ++rf) {
                int row = rf * 16 + l15;
                int off = row * 128 + ((kk * 64 + lhi * 16) ^ ((row & 7) << 4));
                af[rf] = *reinterpret_cast<const short8*>(reinterpret_cast<const char*>(Ah) + off);
            }
            #pragma unroll
            for (int cf = 0; cf < 4; ++cf) {
                int row = w * 64 + cf * 16 + l15;
                int off = row * 128 + ((kk * 64 + lhi * 16) ^ ((row & 7) << 4));
                bfr[cf] = *reinterpret_cast<const short8*>(reinterpret_cast<const char*>(Bw) + off);
            }
            #pragma unroll
            for (int rf = 0; rf < 4; ++rf)
                #pragma unroll
                for (int cf = 0; cf < 4; ++cf)
                    acc[rf][cf] = __builtin_amdgcn_mfma_f32_16x16x32_bf16(af[rf], bfr[cf], acc[rf][cf], 0, 0, 0);
        }
        __syncthreads();
    }
    unsigned short* wb = wht + (size_t)b * DOUT * NN;
    #pragma unroll
    for (int rf = 0; rf < 4; ++rf) {
        #pragma unroll
        for (int cf = 0; cf < 4; ++cf) {
            int d = w * 64 + cf * 16 + l15;
            int m = n0 + rf * 16 + lhi * 4;
            uint2 pk;
            pk.x = (uint32_t)f2bf(acc[rf][cf][0]) | ((uint32_t)f2bf(acc[rf][cf][1]) << 16);
            pk.y = (uint32_t)f2bf(acc[rf][cf][2]) | ((uint32_t)f2bf(acc[rf][cf][3]) << 16);
            *reinterpret_cast<uint2*>(wb + (size_t)d * NN + m) = pk;
        }
    }
    const float* ab = a + b * 2 * DOUT;
    float a1v[4], a2v[4];
    #pragma unroll
    for (int cf = 0; cf < 4; ++cf) {
        int d = w * 64 + cf * 16 + l15;
        a1v[cf] = ab[d];
        a2v[cf] = ab[DOUT + d];
    }
    #pragma unroll
    for (int rf = 0; rf < 4; ++rf) {
        #pragma unroll
        for (int j = 0; j < 4; ++j) {
            float p1 = 0.f, p2 = 0.f;
            #pragma unroll
            for (int cf = 0; cf < 4; ++cf) {
                p1 = fmaf(acc[rf][cf][j], a1v[cf], p1);
                p2 = fmaf(acc[rf][cf][j], a2v[cf], p2);
            }
            #pragma unroll
            for (int msk = 1; msk < 16; msk <<= 1) {
                p1 += __shfl_xor(p1, msk);
                p2 += __shfl_xor(p2, msk);
            }
            if (l15 == 0) {
                atomicAdd(&e1s[rf * 16 + lhi * 4 + j], p1);
                atomicAdd(&e2s[rf * 16 + lhi * 4 + j], p2);
            }
        }
    }
    __syncthreads();
    if (tid < 64) {
        float e1v = e1s[tid], e2v = e2s[tid];
        x1t[b * NN + n0 + tid] = float2{__expf(e1v), __expf(ALPHA_ * e1v)};
        y1t[b * NN + n0 + tid] = __expf(e2v);
        y2t[b * NN + n0 + tid] = __expf(ALPHA_ * e2v);
    }
}

// ---------------- K4: h' numerators, K-split x2; single barrier per tile -----------
// block 64n x 256d x half-K, 512 threads = 8 waves (2n x 4d), each 32n x 64d.
// Pt double-buffered: P(t+1) written to Pt[cur^1] BEFORE MM(t) -> 1 barrier/tile.
// LDS = 64KB Bw dbuf + 16KB Pt dbuf = 81920B -> exactly 2 blocks/CU (160KiB).
// Partials plain-stored (no atomics): T0=0 -> out, T0=1 -> part1 (reused hb).
__global__ __launch_bounds__(512, 4) void k_attn(const unsigned short* __restrict__ wht,
                                                 const uint32_t* __restrict__ bits,
                                                 const float2* __restrict__ x1t,
                                                 const float* __restrict__ y1t,
                                                 const float* __restrict__ y2t,
                                                 float* __restrict__ out,
                                                 float* __restrict__ part1,
                                                 float* __restrict__ sums0,
                                                 float* __restrict__ sums1) {
    __shared__ unsigned short Bw[2 * 256 * 64];  // WhT tile dbuf, swizzled rows (64KB)
    __shared__ unsigned short Pt[2 * 64 * 64];   // P tile dbuf, swizzled rows (16KB)

    const int tid = threadIdx.x;
    const int w = tid >> 6, lane = tid & 63;
    const int l15 = lane & 15, lh4 = lane >> 4;
    const int wn = w >> 2, wd = w & 3;

    // XCD swizzle: 512 blocks; xcd g = (b, n-half); within: 32 n-chunks x 2 k-halves
    const int bid = blockIdx.x;
    const int wg = ((bid & 7) << 6) | (bid >> 3);
    const int g  = wg >> 6;            // XCD id
    const int b  = g >> 1;
    const int n0 = ((g & 1) * 32 + (wg & 31)) << 6;
    const int T0 = ((wg >> 5) & 1) * 32;          // k-half: tiles [T0, T0+32)

    // P mapping: pr = row (0..63), pc = 8-m group (0..7)
    const int pr = tid >> 3, pc = tid & 7;
    const float2 xv = x1t[b * NN + n0 + pr];
    const float X1 = xv.x, X2 = xv.y;
    const unsigned short* wb = wht + (size_t)b * DOUT * NN;

    f32x4 acc[2][4] = {};
    f32x4 accs[2] = {};
    short8 ones;
    {
        union { short8 v; uint32_t u[4]; } ov;
        ov.u[0] = 0x3F803F80u; ov.u[1] = 0x3F803F80u;
        ov.u[2] = 0x3F803F80u; ov.u[3] = 0x3F803F80u;
        ones = ov.v;
    }

    // strength-reduced pointers
    const unsigned short* sp[4];
    #pragma unroll
    for (int it = 0; it < 4; ++it) {
        int q = it * 512 + tid;
        int row = q >> 3, c = q & 7;
        sp[it] = wb + (size_t)row * NN + T0 * 64 + 8 * (c ^ (row & 7));
    }
    const uint8_t* bp = reinterpret_cast<const uint8_t*>(bits) +
                        (size_t)(n0 + pr) * (NN / 8) + T0 * 8 + pc;
    const float4* y1p = reinterpret_cast<const float4*>(y1t + b * NN + T0 * 64 + pc * 8);
    const float4* y2p = reinterpret_cast<const float4*>(y2t + b * NN + T0 * 64 + pc * 8);

#define STAGE(BUF)                                                                     \
    {                                                                                  \
        _Pragma("unroll")                                                              \
        for (int it = 0; it < 4; ++it) {                                               \
            char* dst = reinterpret_cast<char*>(Bw) + (BUF) * 32768 + it * 8192 + w * 1024; \
            __builtin_amdgcn_global_load_lds((gconst_void*)sp[it], (lds_void*)dst, 16, 0, 0); \
            sp[it] += 64;                                                              \
        }                                                                              \
    }

#define P_MATH(BB, Y1A, Y1B, Y2A, Y2B, PKW)                                            \
    {                                                                                  \
        float v1[8] = {Y1A.x, Y1A.y, Y1A.z, Y1A.w, Y1B.x, Y1B.y, Y1B.z, Y1B.w};        \
        float v2[8] = {Y2A.x, Y2A.y, Y2A.z, Y2A.w, Y2B.x, Y2B.y, Y2B.z, Y2B.w};        \
        _Pragma("unroll")                                                              \
        for (int i = 0; i < 4; ++i) {                                                  \
            f32x2 pa = f32x2{v1[2 * i], v1[2 * i + 1]} * X1;                           \
            f32x2 pb = f32x2{v2[2 * i], v2[2 * i + 1]} * X2;                           \
            f32x2 pm = __builtin_elementwise_max(pa, pb);                              \
            union { __hip_bfloat162 h; uint32_t u; } cc;                               \
            cc.h = __float22bfloat162_rn(float2{pm.x, pm.y});                          \
            uint32_t b2 = ((BB) >> (2 * i)) & 3u;                                      \
            uint32_t mk = ((b2 & 1u) ? 0xFFFFu : 0u) | ((b2 & 2u) ? 0xFFFF0000u : 0u); \
            PKW[i] = cc.u & mk;                                                        \
        }                                                                              \
    }

#define PT_WRITE(PKW, BUF)                                                             \
    {                                                                                  \
        uint4 qv; qv.x = PKW[0]; qv.y = PKW[1]; qv.z = PKW[2]; qv.w = PKW[3];          \
        *reinterpret_cast<uint4*>(reinterpret_cast<char*>(Pt) + (BUF) * 8192 +         \
                                  pr * 128 + ((pc * 16) ^ ((pr & 7) << 4))) = qv;      \
    }

#define MM(CUR)                                                                        \
    {                                                                                  \
        const char* bwb = reinterpret_cast<const char*>(Bw) + (CUR) * 32768;           \
        const char* ptb = reinterpret_cast<const char*>(Pt) + (CUR) * 8192;            \
        __builtin_amdgcn_s_setprio(1);                                                 \
        _Pragma("unroll")                                                              \
        for (int kk = 0; kk < 2; ++kk) {                                               \
            short8 af[2], bf[4];                                                       \
            _Pragma("unroll")                                                          \
            for (int rf = 0; rf < 2; ++rf) {                                           \
                int row = wn * 32 + rf * 16 + l15;                                     \
                int off = row * 128 + ((kk * 64 + lh4 * 16) ^ ((row & 7) << 4));       \
                af[rf] = *reinterpret_cast<const short8*>(ptb + off);                  \
            }                                                                          \
            _Pragma("unroll")                                                          \
            for (int cf = 0; cf < 4; ++cf) {                                           \
                int row = wd * 64 + cf * 16 + l15;                                     \
                int off = row * 128 + ((kk * 64 + lh4 * 16) ^ ((row & 7) << 4));       \
                bf[cf] = *reinterpret_cast<const short8*>(bwb + off);                  \
            }                                                                          \
            _Pragma("unroll")                                                          \
            for (int rf = 0; rf < 2; ++rf) {                                           \
                _Pragma("unroll")                                                      \
                for (int cf = 0; cf < 4; ++cf)                                         \
                    acc[rf][cf] = __builtin_amdgcn_mfma_f32_16x16x32_bf16(             \
                        af[rf], bf[cf], acc[rf][cf], 0, 0, 0);                         \
                accs[rf] = __builtin_amdgcn_mfma_f32_16x16x32_bf16(                    \
                    af[rf], ones, accs[rf], 0, 0, 0);                                  \
            }                                                                          \
        }                                                                              \
        __builtin_amdgcn_s_setprio(0);                                                 \
    }

    // ---- prologue: stage + P for first tile of this k-half (both into buf 0) ----
    STAGE(0)
    {
        uint32_t bb = *bp; bp += 8;
        float4 y1a = y1p[0], y1b = y1p[1]; y1p += 16;
        float4 y2a = y2p[0], y2b = y2p[1]; y2p += 16;
        uint32_t pkw[4];
        P_MATH(bb, y1a, y1b, y2a, y2b, pkw)
        PT_WRITE(pkw, 0)
    }
    __syncthreads();

    // ---- main loop over 32 tiles: ONE barrier per tile ----
    for (int t = 0; t < 32; ++t) {
        const int cur = t & 1;
        if (t < 31) {
            STAGE(cur ^ 1)                       // async loads for t+1
            uint32_t bb = *bp; bp += 8;
            float4 y1a = y1p[0], y1b = y1p[1]; y1p += 16;
            float4 y2a = y2p[0], y2b = y2p[1]; y2p += 16;
            uint32_t pkw[4];
            P_MATH(bb, y1a, y1b, y2a, y2b, pkw)  // VALU for t+1
            PT_WRITE(pkw, cur ^ 1)               // Pt[cur^1]: last read ended at t-1
        }
        MM(cur)                                  // MFMA on tile t
        __syncthreads();                         // drains stage + orders Pt write
    }
#undef STAGE
#undef P_MATH
#undef PT_WRITE
#undef MM

    // ---- epilogue: plain stores of partial numerators and row sums ----
    float* pdst = (T0 == 0) ? out : part1;
    #pragma unroll
    for (int rf = 0; rf < 2; ++rf) {
        #pragma unroll
        for (int cf = 0; cf < 4; ++cf) {
            int d = wd * 64 + cf * 16 + l15;
            #pragma unroll
            for (int j = 0; j < 4; ++j) {
                int nr = n0 + wn * 32 + rf * 16 + lh4 * 4 + j;
                pdst[((size_t)b * NN + nr) * DOUT + d] = acc[rf][cf][j];
            }
        }
    }
    if (wd == 0 && l15 == 0) {
        float* sdst = (T0 == 0) ? sums0 : sums1;
        #pragma unroll
        for (int rf = 0; rf < 2; ++rf)
            #pragma unroll
            for (int j = 0; j < 4; ++j) {
                int nr = n0 + wn * 32 + rf * 16 + lh4 * 4 + j;
                sdst[b * NN + nr] = accs[rf][j];
            }
    }
}

// ---------------- K5: finalize — out = ELU((out + part1) / (s0+s1)) ----------------
__global__ __launch_bounds__(256) void k_final(const float* __restrict__ part1,
                                               const float* __restrict__ sums0,
                                               const float* __restrict__ sums1,
                                               float* __restrict__ out) {
    int f4 = blockIdx.x * 256 + threadIdx.x;     // float4 index
    int row = f4 >> 6;                           // 64 float4 per (b,n) row
    float inv = 1.0f / (sums0[row] + sums1[row]);
    float4 v = reinterpret_cast<const float4*>(out)[f4];
    float4 p = reinterpret_cast<const float4*>(part1)[f4];
    v.x = (v.x + p.x) * inv;
    v.y = (v.y + p.y) * inv;
    v.z = (v.z + p.z) * inv;
    v.w = (v.w + p.w) * inv;
    v.x = v.x > 0.f ? v.x : (__expf(v.x) - 1.f);
    v.y = v.y > 0.f ? v.y : (__expf(v.y) - 1.f);
    v.z = v.z > 0.f ? v.z : (__expf(v.z) - 1.f);
    v.w = v.w > 0.f ? v.w : (__expf(v.w) - 1.f);
    reinterpret_cast<float4*>(out)[f4] = v;
}

extern "C" void kernel_launch(void* const* d_in, const int* in_sizes, int n_in,
                              void* d_out, int out_size, void* d_ws, size_t ws_size,
                              hipStream_t stream) {
    (void)in_sizes; (void)n_in; (void)out_size; (void)ws_size;
    const float* h   = (const float*)d_in[0];
    const int*   adj = (const int*)d_in[1];
    const float* Ws  = (const float*)d_in[2];
    const float* a   = (const float*)d_in[3];
    float* out = (float*)d_out;

    char* ws = (char*)d_ws;
    unsigned short* hb  = (unsigned short*)(ws);              // 16,777,216 B (reused as part1)
    unsigned short* wst = (unsigned short*)(ws + 16777216);   //  1,048,576 B
    unsigned short* wht = (unsigned short*)(ws + 17825792);   //  8,388,608 B
    float2* x1t = (float2*)(ws + 26214400);                   //    131,072 B
    float*  y1t = (float*)(ws + 26345472);                    //     65,536 B
    float*  y2t = (float*)(ws + 26411008);                    //     65,536 B
    uint32_t* bits = (uint32_t*)(ws + 26476544);              //  2,097,152 B
    float* sums0 = (float*)(ws + 28573696);                   //     65,536 B
    float* sums1 = (float*)(ws + 28639232);                   //     65,536 B
    float* part1 = (float*)hb;                                // hb dead after k_gemm1

    k_prep<<<dim3(2048), dim3(256), 0, stream>>>(adj, (const float4*)h, Ws,
                                                 bits, (uint2*)hb, wst);
    k_gemm1<<<dim3(NN / 64, B_), dim3(256), 0, stream>>>(hb, wst, a, wht, x1t, y1t, y2t);
    k_attn<<<dim3(512), dim3(512), 0, stream>>>(wht, bits, x1t, y1t, y2t,
                                                out, part1, sums0, sums1);
    k_final<<<dim3(B_ * NN * DOUT / 1024), dim3(256), 0, stream>>>(part1, sums0, sums1, out);
}